// Round 20
// baseline (1058.423 us; speedup 1.0000x reference)
//
#include <hip/hip_runtime.h>

typedef unsigned short ushort_t;
typedef unsigned int uint_t;

typedef __attribute__((ext_vector_type(8))) __bf16 bf16x8_t;
typedef __attribute__((ext_vector_type(8))) short s16x8;
typedef __attribute__((ext_vector_type(4))) float f32x4;

#define T_TOK 2048
#define H_DIM 2048
#define I_DIM 1024
#define N_EXP 64
#define TOPK 8
#define LSTR 40      // LDS row stride in bf16 elems (BK=32 + 8 pad)

// Raw barrier: does NOT drain vmcnt -> in-flight global loads stay outstanding.
#define BAR_RAW()  asm volatile("s_barrier" ::: "memory")
// LDS-visibility barrier: drain ds ops (lgkm) then barrier; vmcnt untouched.
#define BAR_LGKM() asm volatile("s_waitcnt lgkmcnt(0)\n\ts_barrier" ::: "memory")

__device__ inline f32x4 mfma_bf16(s16x8 a, s16x8 b, f32x4 c) {
  return __builtin_amdgcn_mfma_f32_16x16x32_bf16(
      __builtin_bit_cast(bf16x8_t, a), __builtin_bit_cast(bf16x8_t, b), c, 0, 0, 0);
}

__device__ inline ushort_t f2bf(float f) {
  uint_t u = __float_as_uint(f);
  u += 0x7FFFu + ((u >> 16) & 1u);   // round-to-nearest-even
  return (ushort_t)(u >> 16);
}

// packed f32x2 -> bf16x2 (RNE), 1 instruction
__device__ inline uint_t pkbf(float a, float b) {
  uint_t r;
  asm("v_cvt_pk_bf16_f32 %0, %1, %2" : "=v"(r) : "v"(a), "v"(b));
  return r;
}
// float4 -> 4 bf16 (8 B)
__device__ inline uint2 pk4(float4 v) {
  uint2 w;
  w.x = pkbf(v.x, v.y);
  w.y = pkbf(v.z, v.w);
  return w;
}

// XCD-chunk swizzle (bijective when nwg % 8 == 0)
__device__ __forceinline__ int xcd_swizzle(int bid, int nwg) {
  int q = nwg >> 3;
  return (bid & 7) * q + (bid >> 3);
}

// ---------------- Router: logits[t][e] = sum_h x[t][h] * gw[e][h] (fp32 exact) ----------
__global__ __launch_bounds__(256) void router_kernel(const float* __restrict__ X,
                                                     const float* __restrict__ GW,
                                                     float* __restrict__ logits) {
  __shared__ float xs[4][H_DIM];
  int tid = threadIdx.x;
  int t0 = blockIdx.x * 4;
  const float4* src = (const float4*)(X + (size_t)t0 * H_DIM);
  float4* dst = (float4*)(&xs[0][0]);
#pragma unroll
  for (int j = 0; j < 8; ++j) dst[tid + 256 * j] = src[tid + 256 * j];
  __syncthreads();
  int wave = tid >> 6, lane = tid & 63;
  int t = t0 + wave;
  const float4* w = (const float4*)(GW + (size_t)lane * H_DIM);
  const float4* xr = (const float4*)(&xs[wave][0]);
  float acc = 0.f;
  for (int i = 0; i < H_DIM / 4; ++i) {
    float4 a = xr[i];
    float4 b = w[i];
    acc = fmaf(a.x, b.x, acc);
    acc = fmaf(a.y, b.y, acc);
    acc = fmaf(a.z, b.z, acc);
    acc = fmaf(a.w, b.w, acc);
  }
  logits[(size_t)t * N_EXP + lane] = acc;
}

// ---------------- Softmax + top-8 per token (one wave per token) -----------------------
__global__ __launch_bounds__(256) void topk_kernel(const float* __restrict__ logits,
                                                   int* __restrict__ counts,
                                                   int* __restrict__ sel_e,
                                                   float* __restrict__ sel_w) {
  int tid = threadIdx.x;
  int wave = tid >> 6, lane = tid & 63;
  int t = blockIdx.x * 4 + wave;
  float l = logits[(size_t)t * N_EXP + lane];
  float m = l;
#pragma unroll
  for (int s = 32; s; s >>= 1) m = fmaxf(m, __shfl_xor(m, s, 64));
  float p = __expf(l - m);
  float sum = p;
#pragma unroll
  for (int s = 32; s; s >>= 1) sum += __shfl_xor(sum, s, 64);
  float prob = p / sum;

  float val = l;
#pragma unroll
  for (int k = 0; k < TOPK; ++k) {
    float bv = val;
    int bi = lane;
#pragma unroll
    for (int s = 32; s; s >>= 1) {
      float ov = __shfl_xor(bv, s, 64);
      int oi = __shfl_xor(bi, s, 64);
      if (ov > bv || (ov == bv && oi < bi)) { bv = ov; bi = oi; }
    }
    float bw = __shfl(prob, bi, 64);
    if (lane == 0) {
      sel_e[t * TOPK + k] = bi;
      sel_w[t * TOPK + k] = bw;
      atomicAdd(&counts[bi], 1);
    }
    if (lane == bi) val = -INFINITY;
  }
}

// ---------------- Prefix sum over 64 expert counts -------------------------------------
__global__ void scan_kernel(const int* __restrict__ counts, int* __restrict__ offsets,
                            int* __restrict__ cursor) {
  if (threadIdx.x == 0) {
    int acc = 0;
    for (int e = 0; e < N_EXP; ++e) { offsets[e] = acc; acc += counts[e]; }
    offsets[N_EXP] = acc;
  }
  if (threadIdx.x < N_EXP) cursor[threadIdx.x] = 0;
}

// ---------------- Assign packed rows ---------------------------------------------------
__global__ __launch_bounds__(256) void assign_kernel(const int* __restrict__ sel_e,
                                                     const float* __restrict__ sel_w,
                                                     const int* __restrict__ offsets,
                                                     int* __restrict__ cursor,
                                                     int* __restrict__ token_of,
                                                     float* __restrict__ weight_of) {
  int idx = blockIdx.x * 256 + threadIdx.x;  // 0..16383
  int t = idx >> 3;
  int e = sel_e[idx];
  float w = sel_w[idx];
  int r = offsets[e] + atomicAdd(&cursor[e], 1);
  token_of[r] = t;
  weight_of[r] = w;
}

// ---------------- Fused gate+up GEMM + SiLU -> act (bf16), persistent blocks -----------
// grid = 64 experts x 8 nt = 512 blocks (2/CU, all co-resident). Each block OWNS
// its (e,nt) weight panel and loops over the expert's 128-row m-tiles internally:
// panel re-reads are same-block L2-hot, zero dead blocks. Inner schedule = R16
// exact (BK=32, 2-deep register prefetch, 2-barrier, 8 waves 2Mx4N, acc 16 f32x4).
// e-major decomposition + XCD swizzle: the 8 nt-blocks of an expert share an XCD
// -> X-row reads L2-local.
__global__ __launch_bounds__(512, 3) void gateup_kernel(const float* __restrict__ X,
                                                        const float* __restrict__ Wg,
                                                        const float* __restrict__ Wu,
                                                        const int* __restrict__ offsets,
                                                        const int* __restrict__ token_of,
                                                        ushort_t* __restrict__ act) {
  int bid = xcd_swizzle(blockIdx.x, N_EXP * 8);
  int e = bid >> 3;        // e-major: consecutive logical bids share the expert
  int nt = bid & 7;
  int base = offsets[e];
  int Me = offsets[e + 1] - base;
  int nmt = (Me + 127) >> 7;

  __shared__ ushort_t As[128 * LSTR];   // 10 KB
  __shared__ ushort_t Bgs[128 * LSTR];  // 10 KB
  __shared__ ushort_t Bus[128 * LSTR];  // 10 KB
  __shared__ int stok[128];

  int tid = threadIdx.x;
  int wave = tid >> 6, lane = tid & 63;
  int wm = wave >> 2, wn = wave & 3;
  int sr = tid >> 2, sc = (tid & 3) * 8;
  int fr = lane & 15, q2 = lane >> 4;

  const float* pG = Wg + ((size_t)e * I_DIM + nt * 128 + sr) * H_DIM + sc;
  const float* pU = Wu + ((size_t)e * I_DIM + nt * 128 + sr) * H_DIM + sc;

  const int NK = H_DIM / 32;  // 64 (even)

#define GU_COMPUTE()                                                                \
  {                                                                                 \
    s16x8 af[4], bg[2], bu[2];                                                      \
    _Pragma("unroll")                                                               \
    for (int mf = 0; mf < 4; ++mf)                                                  \
      af[mf] = *(const s16x8*)&As[(wm * 64 + mf * 16 + fr) * LSTR + q2 * 8];        \
    _Pragma("unroll")                                                               \
    for (int nf = 0; nf < 2; ++nf) {                                                \
      bg[nf] = *(const s16x8*)&Bgs[(wn * 32 + nf * 16 + fr) * LSTR + q2 * 8];       \
      bu[nf] = *(const s16x8*)&Bus[(wn * 32 + nf * 16 + fr) * LSTR + q2 * 8];       \
    }                                                                               \
    __builtin_amdgcn_s_setprio(1);                                                  \
    _Pragma("unroll")                                                               \
    for (int mf = 0; mf < 4; ++mf)                                                  \
      _Pragma("unroll")                                                             \
      for (int nf = 0; nf < 2; ++nf) {                                              \
        accg[mf][nf] = mfma_bf16(af[mf], bg[nf], accg[mf][nf]);                     \
        accu[mf][nf] = mfma_bf16(af[mf], bu[nf], accu[mf][nf]);                     \
      }                                                                             \
    __builtin_amdgcn_s_setprio(0);                                                  \
  }

  for (int mt = 0; mt < nmt; ++mt) {
    __syncthreads();   // all waves done with previous m-tile's LDS + stok
    if (tid < 128) {
      int gm = mt * 128 + tid;
      stok[tid] = token_of[base + (gm < Me ? gm : Me - 1)];
    }
    __syncthreads();
    const float* pA = X + (size_t)stok[sr] * H_DIM + sc;

    f32x4 accg[4][2], accu[4][2];
#pragma unroll
    for (int i = 0; i < 4; ++i)
#pragma unroll
      for (int j = 0; j < 2; ++j) { accg[i][j] = (f32x4)0.f; accu[i][j] = (f32x4)0.f; }

    // 2-deep prefetch: set0 = even tiles, set1 = odd tiles
    float4 a0[2], g0[2], u0[2], a1[2], g1[2], u1[2];
#pragma unroll
    for (int j = 0; j < 2; ++j) {
      a0[j] = *(const float4*)(pA + 4 * j);
      g0[j] = *(const float4*)(pG + 4 * j);
      u0[j] = *(const float4*)(pU + 4 * j);
      a1[j] = *(const float4*)(pA + 32 + 4 * j);
      g1[j] = *(const float4*)(pG + 32 + 4 * j);
      u1[j] = *(const float4*)(pU + 32 + 4 * j);
    }

    for (int k = 0; k < NK; k += 2) {
      // even tile k (set0): ds_write's vmcnt wait targets loads issued at k-2
      BAR_RAW();
      *(uint2*)&As[sr * LSTR + sc] = pk4(a0[0]);
      *(uint2*)&As[sr * LSTR + sc + 4] = pk4(a0[1]);
      *(uint2*)&Bgs[sr * LSTR + sc] = pk4(g0[0]);
      *(uint2*)&Bgs[sr * LSTR + sc + 4] = pk4(g0[1]);
      *(uint2*)&Bus[sr * LSTR + sc] = pk4(u0[0]);
      *(uint2*)&Bus[sr * LSTR + sc + 4] = pk4(u0[1]);
      if (k + 2 < NK) {
        int kn = (k + 2) * 32;
#pragma unroll
        for (int j = 0; j < 2; ++j) {
          a0[j] = *(const float4*)(pA + kn + 4 * j);
          g0[j] = *(const float4*)(pG + kn + 4 * j);
          u0[j] = *(const float4*)(pU + kn + 4 * j);
        }
      }
      BAR_LGKM();
      GU_COMPUTE();

      // odd tile k+1 (set1)
      BAR_RAW();
      *(uint2*)&As[sr * LSTR + sc] = pk4(a1[0]);
      *(uint2*)&As[sr * LSTR + sc + 4] = pk4(a1[1]);
      *(uint2*)&Bgs[sr * LSTR + sc] = pk4(g1[0]);
      *(uint2*)&Bgs[sr * LSTR + sc + 4] = pk4(g1[1]);
      *(uint2*)&Bus[sr * LSTR + sc] = pk4(u1[0]);
      *(uint2*)&Bus[sr * LSTR + sc + 4] = pk4(u1[1]);
      if (k + 3 < NK) {
        int kn = (k + 3) * 32;
#pragma unroll
        for (int j = 0; j < 2; ++j) {
          a1[j] = *(const float4*)(pA + kn + 4 * j);
          g1[j] = *(const float4*)(pG + kn + 4 * j);
          u1[j] = *(const float4*)(pU + kn + 4 * j);
        }
      }
      BAR_LGKM();
      GU_COMPUTE();
    }

    // epilogue: act = silu(g)*u -> bf16
#pragma unroll
    for (int mf = 0; mf < 4; ++mf)
#pragma unroll
      for (int nf = 0; nf < 2; ++nf) {
        f32x4 g = accg[mf][nf], u = accu[mf][nf];
#pragma unroll
        for (int r = 0; r < 4; ++r) {
          int mloc = wm * 64 + mf * 16 + q2 * 4 + r;
          int gm = mt * 128 + mloc;
          if (gm < Me) {
            float gv = g[r], uv = u[r];
            float s = gv / (1.f + __expf(-gv));
            int col = nt * 128 + wn * 32 + nf * 16 + fr;
            act[(size_t)(base + gm) * I_DIM + col] = f2bf(s * uv);
          }
        }
      }
  }
#undef GU_COMPUTE
}

// ---------------- Down GEMM + weighted scatter, persistent blocks ----------------------
// grid = 64 experts x 16 nt = 1024 blocks. Each block owns its (e,nt) Wd panel,
// loops over the expert's 256-row m-tiles internally. Inner schedule = R17 exact
// (M=256, BK=32, 1-deep prefetch, acc 16 f32x4).
__global__ __launch_bounds__(512, 3) void down_kernel(const ushort_t* __restrict__ act,
                                                      const float* __restrict__ Wd,
                                                      const int* __restrict__ offsets,
                                                      const int* __restrict__ token_of,
                                                      const float* __restrict__ weight_of,
                                                      float* __restrict__ out) {
  int bid = xcd_swizzle(blockIdx.x, N_EXP * 16);
  int e = bid >> 4;        // e-major
  int nt = bid & 15;
  int base = offsets[e];
  int Me = offsets[e + 1] - base;
  int nmt = (Me + 255) >> 8;

  __shared__ ushort_t As[256 * LSTR];   // 20 KB
  __shared__ ushort_t Bs[128 * LSTR];   // 10 KB
  __shared__ int stok[256];
  __shared__ float sw[256];

  int tid = threadIdx.x;
  int wave = tid >> 6, lane = tid & 63;
  int wm = wave >> 2, wn = wave & 3;
  int fr = lane & 15, q2 = lane >> 4;

  // A (act, bf16): 2 thr/row x 256 rows; 16 bf16 (32 B = 2 s16x8) at (tid&1)*16.
  int sa = tid >> 1;
  int ca = (tid & 1) * 16;
  // B (Wd, fp32): 4 thr/row x 128 rows; 8 floats at (tid&3)*8.
  int sb = tid >> 2, cb = (tid & 3) * 8;
  const float* pB = Wd + ((size_t)e * H_DIM + nt * 128 + sb) * I_DIM + cb;

  for (int mt = 0; mt < nmt; ++mt) {
    __syncthreads();   // all waves done with previous m-tile's LDS/stok/sw (epilogue reads them)
    if (tid < 256) {
      int gm = mt * 256 + tid;
      int ok = gm < Me;
      int cm = ok ? gm : (Me - 1);
      stok[tid] = token_of[base + cm];
      sw[tid] = ok ? weight_of[base + gm] : 0.f;
    }
    __syncthreads();

    int r0 = mt * 256 + sa;
    if (r0 >= Me) r0 = Me - 1;
    const ushort_t* pA = act + (size_t)(base + r0) * I_DIM + ca;

    f32x4 acc[8][2];
#pragma unroll
    for (int i = 0; i < 8; ++i)
#pragma unroll
      for (int j = 0; j < 2; ++j) acc[i][j] = (f32x4)0.f;

    s16x8 rA[2];
    float4 rB[2];
    rA[0] = *(const s16x8*)pA;
    rA[1] = *(const s16x8*)(pA + 8);
#pragma unroll
    for (int j = 0; j < 2; ++j) rB[j] = *(const float4*)(pB + 4 * j);

    for (int k0 = 0; k0 < I_DIM; k0 += 32) {
      BAR_RAW();
      *(s16x8*)&As[sa * LSTR + ca] = rA[0];
      *(s16x8*)&As[sa * LSTR + ca + 8] = rA[1];
      *(uint2*)&Bs[sb * LSTR + cb] = pk4(rB[0]);
      *(uint2*)&Bs[sb * LSTR + cb + 4] = pk4(rB[1]);
      if (k0 + 32 < I_DIM) {
        int kn = k0 + 32;
        rA[0] = *(const s16x8*)(pA + kn);
        rA[1] = *(const s16x8*)(pA + kn + 8);
#pragma unroll
        for (int j = 0; j < 2; ++j) rB[j] = *(const float4*)(pB + kn + 4 * j);
      }
      BAR_LGKM();

      s16x8 bf[2];
#pragma unroll
      for (int nf = 0; nf < 2; ++nf)
        bf[nf] = *(const s16x8*)&Bs[(wn * 32 + nf * 16 + fr) * LSTR + q2 * 8];
      __builtin_amdgcn_s_setprio(1);
#pragma unroll
      for (int mf = 0; mf < 8; ++mf) {
        s16x8 af = *(const s16x8*)&As[(wm * 128 + mf * 16 + fr) * LSTR + q2 * 8];
#pragma unroll
        for (int nf = 0; nf < 2; ++nf)
          acc[mf][nf] = mfma_bf16(af, bf[nf], acc[mf][nf]);
      }
      __builtin_amdgcn_s_setprio(0);
    }

#pragma unroll
    for (int mf = 0; mf < 8; ++mf)
#pragma unroll
      for (int nf = 0; nf < 2; ++nf) {
        f32x4 v = acc[mf][nf];
#pragma unroll
        for (int r = 0; r < 4; ++r) {
          int mloc = wm * 128 + mf * 16 + q2 * 4 + r;
          int gm = mt * 256 + mloc;
          if (gm < Me) {
            int t = stok[mloc];
            float w = sw[mloc];
            int h = nt * 128 + wn * 32 + nf * 16 + fr;
            unsafeAtomicAdd(&out[(size_t)t * H_DIM + h], w * v[r]);
          }
        }
      }
  }
}

// ---------------------------------------------------------------------------------------
extern "C" void kernel_launch(void* const* d_in, const int* in_sizes, int n_in,
                              void* d_out, int out_size, void* d_ws, size_t ws_size,
                              hipStream_t stream) {
  const float* X = (const float*)d_in[0];
  const float* GW = (const float*)d_in[1];
  const float* Wg = (const float*)d_in[2];
  const float* Wu = (const float*)d_in[3];
  const float* Wd = (const float*)d_in[4];
  float* out = (float*)d_out;
  float* logits = out + (size_t)T_TOK * H_DIM;

  char* ws = (char*)d_ws;
  int* counts = (int*)ws;                       // 256 B
  int* cursor = (int*)(ws + 256);               // 256 B
  int* offsets = (int*)(ws + 512);              // 260 B
  int* sel_e = (int*)(ws + 1024);               // 64 KB
  float* sel_w = (float*)(ws + 1024 + 65536);   // 64 KB
  int* token_of = (int*)(ws + 1024 + 2 * 65536);
  float* weight_of = (float*)(ws + 1024 + 3 * 65536);
  ushort_t* act = (ushort_t*)(ws + 524288);     // 16384*1024*2 = 32 MB

  hipMemsetAsync(out, 0, (size_t)T_TOK * H_DIM * sizeof(float), stream);
  hipMemsetAsync(ws, 0, 1024, stream);

  router_kernel<<<T_TOK / 4, 256, 0, stream>>>(X, GW, logits);
  topk_kernel<<<T_TOK / 4, 256, 0, stream>>>(logits, counts, sel_e, sel_w);
  scan_kernel<<<1, 64, 0, stream>>>(counts, offsets, cursor);
  assign_kernel<<<(T_TOK * TOPK) / 256, 256, 0, stream>>>(sel_e, sel_w, offsets, cursor,
                                                          token_of, weight_of);
  gateup_kernel<<<N_EXP * 8, 512, 0, stream>>>(X, Wg, Wu, offsets, token_of, act);
  down_kernel<<<N_EXP * 16, 512, 0, stream>>>(act, Wd, offsets, token_of,
                                              weight_of, out);
}

// Round 21
// 819.360 us; speedup vs baseline: 1.2918x; 1.2918x over previous
//
#include <hip/hip_runtime.h>

typedef unsigned short ushort_t;
typedef unsigned int uint_t;

typedef __attribute__((ext_vector_type(8))) __bf16 bf16x8_t;
typedef __attribute__((ext_vector_type(8))) short s16x8;
typedef __attribute__((ext_vector_type(4))) float f32x4;

#define T_TOK 2048
#define H_DIM 2048
#define I_DIM 1024
#define N_EXP 64
#define TOPK 8
#define MT 6         // gateup: 128-row m-tiles (covers 768 tokens/expert)
#define MTG 3        // down: 256-row m-tiles
#define LSTR 40      // LDS row stride in bf16 elems (BK=32 + 8 pad)

// Raw barrier: does NOT drain vmcnt -> in-flight global loads stay outstanding.
#define BAR_RAW()  asm volatile("s_barrier" ::: "memory")
// LDS-visibility barrier: drain ds ops (lgkm) then barrier; vmcnt untouched.
#define BAR_LGKM() asm volatile("s_waitcnt lgkmcnt(0)\n\ts_barrier" ::: "memory")

__device__ inline f32x4 mfma_bf16(s16x8 a, s16x8 b, f32x4 c) {
  return __builtin_amdgcn_mfma_f32_16x16x32_bf16(
      __builtin_bit_cast(bf16x8_t, a), __builtin_bit_cast(bf16x8_t, b), c, 0, 0, 0);
}

__device__ inline ushort_t f2bf(float f) {
  uint_t u = __float_as_uint(f);
  u += 0x7FFFu + ((u >> 16) & 1u);   // round-to-nearest-even
  return (ushort_t)(u >> 16);
}

// packed f32x2 -> bf16x2 (RNE), 1 instruction
__device__ inline uint_t pkbf(float a, float b) {
  uint_t r;
  asm("v_cvt_pk_bf16_f32 %0, %1, %2" : "=v"(r) : "v"(a), "v"(b));
  return r;
}
// float4 -> 4 bf16 (8 B)
__device__ inline uint2 pk4(float4 v) {
  uint2 w;
  w.x = pkbf(v.x, v.y);
  w.y = pkbf(v.z, v.w);
  return w;
}

// XCD-chunk swizzle (bijective when nwg % 8 == 0)
__device__ __forceinline__ int xcd_swizzle(int bid, int nwg) {
  int q = nwg >> 3;
  return (bid & 7) * q + (bid >> 3);
}

// ---------------- Router: logits[t][e] = sum_h x[t][h] * gw[e][h] (fp32 exact) ----------
// 4-accumulator ILP: breaks the serial dependent-FMA chain (latency-bound at
// 4cy x 2048) into 4 independent chains -> throughput-bound.
__global__ __launch_bounds__(256) void router_kernel(const float* __restrict__ X,
                                                     const float* __restrict__ GW,
                                                     float* __restrict__ logits) {
  __shared__ float xs[4][H_DIM];
  int tid = threadIdx.x;
  int t0 = blockIdx.x * 4;
  const float4* src = (const float4*)(X + (size_t)t0 * H_DIM);
  float4* dst = (float4*)(&xs[0][0]);
#pragma unroll
  for (int j = 0; j < 8; ++j) dst[tid + 256 * j] = src[tid + 256 * j];
  __syncthreads();
  int wave = tid >> 6, lane = tid & 63;
  int t = t0 + wave;
  const float4* w = (const float4*)(GW + (size_t)lane * H_DIM);
  const float4* xr = (const float4*)(&xs[wave][0]);
  float ac0 = 0.f, ac1 = 0.f, ac2 = 0.f, ac3 = 0.f;
  for (int i = 0; i < H_DIM / 16; ++i) {   // 128 iters, 4 float4 each
    float4 a0 = xr[4 * i + 0], b0 = w[4 * i + 0];
    float4 a1 = xr[4 * i + 1], b1 = w[4 * i + 1];
    float4 a2 = xr[4 * i + 2], b2 = w[4 * i + 2];
    float4 a3 = xr[4 * i + 3], b3 = w[4 * i + 3];
    ac0 = fmaf(a0.x, b0.x, ac0); ac0 = fmaf(a0.y, b0.y, ac0);
    ac0 = fmaf(a0.z, b0.z, ac0); ac0 = fmaf(a0.w, b0.w, ac0);
    ac1 = fmaf(a1.x, b1.x, ac1); ac1 = fmaf(a1.y, b1.y, ac1);
    ac1 = fmaf(a1.z, b1.z, ac1); ac1 = fmaf(a1.w, b1.w, ac1);
    ac2 = fmaf(a2.x, b2.x, ac2); ac2 = fmaf(a2.y, b2.y, ac2);
    ac2 = fmaf(a2.z, b2.z, ac2); ac2 = fmaf(a2.w, b2.w, ac2);
    ac3 = fmaf(a3.x, b3.x, ac3); ac3 = fmaf(a3.y, b3.y, ac3);
    ac3 = fmaf(a3.z, b3.z, ac3); ac3 = fmaf(a3.w, b3.w, ac3);
  }
  logits[(size_t)t * N_EXP + lane] = (ac0 + ac1) + (ac2 + ac3);
}

// ---------------- Softmax + top-8 per token (one wave per token) -----------------------
__global__ __launch_bounds__(256) void topk_kernel(const float* __restrict__ logits,
                                                   int* __restrict__ counts,
                                                   int* __restrict__ sel_e,
                                                   float* __restrict__ sel_w) {
  int tid = threadIdx.x;
  int wave = tid >> 6, lane = tid & 63;
  int t = blockIdx.x * 4 + wave;
  float l = logits[(size_t)t * N_EXP + lane];
  float m = l;
#pragma unroll
  for (int s = 32; s; s >>= 1) m = fmaxf(m, __shfl_xor(m, s, 64));
  float p = __expf(l - m);
  float sum = p;
#pragma unroll
  for (int s = 32; s; s >>= 1) sum += __shfl_xor(sum, s, 64);
  float prob = p / sum;

  float val = l;
#pragma unroll
  for (int k = 0; k < TOPK; ++k) {
    float bv = val;
    int bi = lane;
#pragma unroll
    for (int s = 32; s; s >>= 1) {
      float ov = __shfl_xor(bv, s, 64);
      int oi = __shfl_xor(bi, s, 64);
      if (ov > bv || (ov == bv && oi < bi)) { bv = ov; bi = oi; }
    }
    float bw = __shfl(prob, bi, 64);
    if (lane == 0) {
      sel_e[t * TOPK + k] = bi;
      sel_w[t * TOPK + k] = bw;
      atomicAdd(&counts[bi], 1);
    }
    if (lane == bi) val = -INFINITY;
  }
}

// ---------------- Prefix sum over 64 expert counts -------------------------------------
__global__ void scan_kernel(const int* __restrict__ counts, int* __restrict__ offsets,
                            int* __restrict__ cursor) {
  if (threadIdx.x == 0) {
    int acc = 0;
    for (int e = 0; e < N_EXP; ++e) { offsets[e] = acc; acc += counts[e]; }
    offsets[N_EXP] = acc;
  }
  if (threadIdx.x < N_EXP) cursor[threadIdx.x] = 0;
}

// ---------------- Assign packed rows ---------------------------------------------------
__global__ __launch_bounds__(256) void assign_kernel(const int* __restrict__ sel_e,
                                                     const float* __restrict__ sel_w,
                                                     const int* __restrict__ offsets,
                                                     int* __restrict__ cursor,
                                                     int* __restrict__ token_of,
                                                     float* __restrict__ weight_of) {
  int idx = blockIdx.x * 256 + threadIdx.x;  // 0..16383
  int t = idx >> 3;
  int e = sel_e[idx];
  float w = sel_w[idx];
  int r = offsets[e] + atomicAdd(&cursor[e], 1);
  token_of[r] = t;
  weight_of[r] = w;
}

// ---------------- Fused gate+up GEMM + SiLU -> act (bf16) — R18/R16 exact --------------
// 512 thr, tile 128(M)x128(N) x2 proj, BK=32, 8 waves (2M x 4N), wave 64x32/proj
// (acc = 16 f32x4), 2-deep register prefetch, (512,3), nt-fastest + XCD swizzle.
__global__ __launch_bounds__(512, 3) void gateup_kernel(const float* __restrict__ X,
                                                        const float* __restrict__ Wg,
                                                        const float* __restrict__ Wu,
                                                        const int* __restrict__ offsets,
                                                        const int* __restrict__ token_of,
                                                        ushort_t* __restrict__ act) {
  int bid = xcd_swizzle(blockIdx.x, N_EXP * MT * 8);
  int e = bid / (MT * 8);
  int mt = (bid % (MT * 8)) / 8;   // nt fastest
  int nt = bid % 8;
  int base = offsets[e];
  int Me = offsets[e + 1] - base;
  if (mt * 128 >= Me) return;

  __shared__ ushort_t As[128 * LSTR];   // 10 KB
  __shared__ ushort_t Bgs[128 * LSTR];  // 10 KB
  __shared__ ushort_t Bus[128 * LSTR];  // 10 KB
  __shared__ int stok[128];

  int tid = threadIdx.x;
  if (tid < 128) {
    int gm = mt * 128 + tid;
    int cm = gm < Me ? gm : (Me - 1);
    stok[tid] = token_of[base + cm];
  }
  __syncthreads();

  int wave = tid >> 6, lane = tid & 63;
  int wm = wave >> 2, wn = wave & 3;

  int sr = tid >> 2, sc = (tid & 3) * 8;
  const float* pA = X + (size_t)stok[sr] * H_DIM + sc;
  const float* pG = Wg + ((size_t)e * I_DIM + nt * 128 + sr) * H_DIM + sc;
  const float* pU = Wu + ((size_t)e * I_DIM + nt * 128 + sr) * H_DIM + sc;

  f32x4 accg[4][2], accu[4][2];
#pragma unroll
  for (int i = 0; i < 4; ++i)
#pragma unroll
    for (int j = 0; j < 2; ++j) { accg[i][j] = (f32x4)0.f; accu[i][j] = (f32x4)0.f; }

  // 2-deep prefetch: set0 = even tiles, set1 = odd tiles
  float4 a0[2], g0[2], u0[2], a1[2], g1[2], u1[2];
#pragma unroll
  for (int j = 0; j < 2; ++j) {
    a0[j] = *(const float4*)(pA + 4 * j);
    g0[j] = *(const float4*)(pG + 4 * j);
    u0[j] = *(const float4*)(pU + 4 * j);
    a1[j] = *(const float4*)(pA + 32 + 4 * j);
    g1[j] = *(const float4*)(pG + 32 + 4 * j);
    u1[j] = *(const float4*)(pU + 32 + 4 * j);
  }

  int fr = lane & 15, q2 = lane >> 4;
  const int NK = H_DIM / 32;  // 64 (even)

#define GU_COMPUTE()                                                                \
  {                                                                                 \
    s16x8 af[4], bg[2], bu[2];                                                      \
    _Pragma("unroll")                                                               \
    for (int mf = 0; mf < 4; ++mf)                                                  \
      af[mf] = *(const s16x8*)&As[(wm * 64 + mf * 16 + fr) * LSTR + q2 * 8];        \
    _Pragma("unroll")                                                               \
    for (int nf = 0; nf < 2; ++nf) {                                                \
      bg[nf] = *(const s16x8*)&Bgs[(wn * 32 + nf * 16 + fr) * LSTR + q2 * 8];       \
      bu[nf] = *(const s16x8*)&Bus[(wn * 32 + nf * 16 + fr) * LSTR + q2 * 8];       \
    }                                                                               \
    __builtin_amdgcn_s_setprio(1);                                                  \
    _Pragma("unroll")                                                               \
    for (int mf = 0; mf < 4; ++mf)                                                  \
      _Pragma("unroll")                                                             \
      for (int nf = 0; nf < 2; ++nf) {                                              \
        accg[mf][nf] = mfma_bf16(af[mf], bg[nf], accg[mf][nf]);                     \
        accu[mf][nf] = mfma_bf16(af[mf], bu[nf], accu[mf][nf]);                     \
      }                                                                             \
    __builtin_amdgcn_s_setprio(0);                                                  \
  }

  for (int k = 0; k < NK; k += 2) {
    // even tile k (set0): ds_write's vmcnt wait targets loads issued at k-2
    BAR_RAW();
    *(uint2*)&As[sr * LSTR + sc] = pk4(a0[0]);
    *(uint2*)&As[sr * LSTR + sc + 4] = pk4(a0[1]);
    *(uint2*)&Bgs[sr * LSTR + sc] = pk4(g0[0]);
    *(uint2*)&Bgs[sr * LSTR + sc + 4] = pk4(g0[1]);
    *(uint2*)&Bus[sr * LSTR + sc] = pk4(u0[0]);
    *(uint2*)&Bus[sr * LSTR + sc + 4] = pk4(u0[1]);
    if (k + 2 < NK) {
      int kn = (k + 2) * 32;
#pragma unroll
      for (int j = 0; j < 2; ++j) {
        a0[j] = *(const float4*)(pA + kn + 4 * j);
        g0[j] = *(const float4*)(pG + kn + 4 * j);
        u0[j] = *(const float4*)(pU + kn + 4 * j);
      }
    }
    BAR_LGKM();
    GU_COMPUTE();

    // odd tile k+1 (set1)
    BAR_RAW();
    *(uint2*)&As[sr * LSTR + sc] = pk4(a1[0]);
    *(uint2*)&As[sr * LSTR + sc + 4] = pk4(a1[1]);
    *(uint2*)&Bgs[sr * LSTR + sc] = pk4(g1[0]);
    *(uint2*)&Bgs[sr * LSTR + sc + 4] = pk4(g1[1]);
    *(uint2*)&Bus[sr * LSTR + sc] = pk4(u1[0]);
    *(uint2*)&Bus[sr * LSTR + sc + 4] = pk4(u1[1]);
    if (k + 3 < NK) {
      int kn = (k + 3) * 32;
#pragma unroll
      for (int j = 0; j < 2; ++j) {
        a1[j] = *(const float4*)(pA + kn + 4 * j);
        g1[j] = *(const float4*)(pG + kn + 4 * j);
        u1[j] = *(const float4*)(pU + kn + 4 * j);
      }
    }
    BAR_LGKM();
    GU_COMPUTE();
  }

  // epilogue: act = silu(g)*u -> bf16
#pragma unroll
  for (int mf = 0; mf < 4; ++mf)
#pragma unroll
    for (int nf = 0; nf < 2; ++nf) {
      f32x4 g = accg[mf][nf], u = accu[mf][nf];
#pragma unroll
      for (int r = 0; r < 4; ++r) {
        int mloc = wm * 64 + mf * 16 + q2 * 4 + r;
        int gm = mt * 128 + mloc;
        if (gm < Me) {
          float gv = g[r], uv = u[r];
          float s = gv / (1.f + __expf(-gv));
          int col = nt * 128 + wn * 32 + nf * 16 + fr;
          act[(size_t)(base + gm) * I_DIM + col] = f2bf(s * uv);
        }
      }
    }
#undef GU_COMPUTE
}

// ---------------- Down GEMM + weighted scatter — R17 base + 2-deep prefetch ------------
// tile 256(M)x128(N), BK=32, 512 thr, 8 waves (2M x 4N), per-wave 128x32 ->
// acc = 16 f32x4 (64 AGPR). (512,3). NEW: 2-deep register prefetch (the
// R15->R16 isolated -6% lever, never applied to the M=256 down).
__global__ __launch_bounds__(512, 3) void down_kernel(const ushort_t* __restrict__ act,
                                                      const float* __restrict__ Wd,
                                                      const int* __restrict__ offsets,
                                                      const int* __restrict__ token_of,
                                                      const float* __restrict__ weight_of,
                                                      float* __restrict__ out) {
  int bid = xcd_swizzle(blockIdx.x, N_EXP * MTG * 16);
  int e = bid / (MTG * 16);
  int mt = (bid % (MTG * 16)) / 16;  // nt fastest
  int nt = bid % 16;
  int base = offsets[e];
  int Me = offsets[e + 1] - base;
  if (mt * 256 >= Me) return;

  __shared__ ushort_t As[256 * LSTR];   // 20 KB
  __shared__ ushort_t Bs[128 * LSTR];   // 10 KB
  __shared__ int stok[256];
  __shared__ float sw[256];

  int tid = threadIdx.x;
  if (tid < 256) {
    int gm = mt * 256 + tid;
    int ok = gm < Me;
    int cm = ok ? gm : (Me - 1);
    stok[tid] = token_of[base + cm];
    sw[tid] = ok ? weight_of[base + gm] : 0.f;
  }
  __syncthreads();

  int wave = tid >> 6, lane = tid & 63;
  int wm = wave >> 2, wn = wave & 3;

  // A (act, bf16): 2 thr/row x 256 rows; 16 bf16 (32 B = 2 s16x8) at (tid&1)*16.
  int sa = tid >> 1;
  int ca = (tid & 1) * 16;
  int r0 = mt * 256 + sa;
  if (r0 >= Me) r0 = Me - 1;
  const ushort_t* pA = act + (size_t)(base + r0) * I_DIM + ca;
  // B (Wd, fp32): 4 thr/row x 128 rows; 8 floats at (tid&3)*8.
  int sb = tid >> 2, cb = (tid & 3) * 8;
  const float* pB = Wd + ((size_t)e * H_DIM + nt * 128 + sb) * I_DIM + cb;

  f32x4 acc[8][2];
#pragma unroll
  for (int i = 0; i < 8; ++i)
#pragma unroll
    for (int j = 0; j < 2; ++j) acc[i][j] = (f32x4)0.f;

  // 2-deep prefetch: set0 = even tiles, set1 = odd tiles
  s16x8 rA0[2], rA1[2];
  float4 rB0[2], rB1[2];
  rA0[0] = *(const s16x8*)pA;
  rA0[1] = *(const s16x8*)(pA + 8);
  rA1[0] = *(const s16x8*)(pA + 32);
  rA1[1] = *(const s16x8*)(pA + 40);
#pragma unroll
  for (int j = 0; j < 2; ++j) {
    rB0[j] = *(const float4*)(pB + 4 * j);
    rB1[j] = *(const float4*)(pB + 32 + 4 * j);
  }

  int fr = lane & 15, q2 = lane >> 4;
  const int NK = I_DIM / 32;  // 32 (even)

#define DN_COMPUTE()                                                                \
  {                                                                                 \
    s16x8 bf[2];                                                                    \
    _Pragma("unroll")                                                               \
    for (int nf = 0; nf < 2; ++nf)                                                  \
      bf[nf] = *(const s16x8*)&Bs[(wn * 32 + nf * 16 + fr) * LSTR + q2 * 8];        \
    __builtin_amdgcn_s_setprio(1);                                                  \
    _Pragma("unroll")                                                               \
    for (int mf = 0; mf < 8; ++mf) {                                                \
      s16x8 af = *(const s16x8*)&As[(wm * 128 + mf * 16 + fr) * LSTR + q2 * 8];     \
      _Pragma("unroll")                                                             \
      for (int nf = 0; nf < 2; ++nf)                                                \
        acc[mf][nf] = mfma_bf16(af, bf[nf], acc[mf][nf]);                           \
    }                                                                               \
    __builtin_amdgcn_s_setprio(0);                                                  \
  }

  for (int k = 0; k < NK; k += 2) {
    // even tile k (set0)
    BAR_RAW();
    *(s16x8*)&As[sa * LSTR + ca] = rA0[0];
    *(s16x8*)&As[sa * LSTR + ca + 8] = rA0[1];
    *(uint2*)&Bs[sb * LSTR + cb] = pk4(rB0[0]);
    *(uint2*)&Bs[sb * LSTR + cb + 4] = pk4(rB0[1]);
    if (k + 2 < NK) {
      int kn = (k + 2) * 32;
      rA0[0] = *(const s16x8*)(pA + kn);
      rA0[1] = *(const s16x8*)(pA + kn + 8);
#pragma unroll
      for (int j = 0; j < 2; ++j) rB0[j] = *(const float4*)(pB + kn + 4 * j);
    }
    BAR_LGKM();
    DN_COMPUTE();

    // odd tile k+1 (set1)
    BAR_RAW();
    *(s16x8*)&As[sa * LSTR + ca] = rA1[0];
    *(s16x8*)&As[sa * LSTR + ca + 8] = rA1[1];
    *(uint2*)&Bs[sb * LSTR + cb] = pk4(rB1[0]);
    *(uint2*)&Bs[sb * LSTR + cb + 4] = pk4(rB1[1]);
    if (k + 3 < NK) {
      int kn = (k + 3) * 32;
      rA1[0] = *(const s16x8*)(pA + kn);
      rA1[1] = *(const s16x8*)(pA + kn + 8);
#pragma unroll
      for (int j = 0; j < 2; ++j) rB1[j] = *(const float4*)(pB + kn + 4 * j);
    }
    BAR_LGKM();
    DN_COMPUTE();
  }

#pragma unroll
  for (int mf = 0; mf < 8; ++mf)
#pragma unroll
    for (int nf = 0; nf < 2; ++nf) {
      f32x4 v = acc[mf][nf];
#pragma unroll
      for (int r = 0; r < 4; ++r) {
        int mloc = wm * 128 + mf * 16 + q2 * 4 + r;
        int gm = mt * 256 + mloc;
        if (gm < Me) {
          int t = stok[mloc];
          float w = sw[mloc];
          int h = nt * 128 + wn * 32 + nf * 16 + fr;
          unsafeAtomicAdd(&out[(size_t)t * H_DIM + h], w * v[r]);
        }
      }
    }
#undef DN_COMPUTE
}

// ---------------------------------------------------------------------------------------
extern "C" void kernel_launch(void* const* d_in, const int* in_sizes, int n_in,
                              void* d_out, int out_size, void* d_ws, size_t ws_size,
                              hipStream_t stream) {
  const float* X = (const float*)d_in[0];
  const float* GW = (const float*)d_in[1];
  const float* Wg = (const float*)d_in[2];
  const float* Wu = (const float*)d_in[3];
  const float* Wd = (const float*)d_in[4];
  float* out = (float*)d_out;
  float* logits = out + (size_t)T_TOK * H_DIM;

  char* ws = (char*)d_ws;
  int* counts = (int*)ws;                       // 256 B
  int* cursor = (int*)(ws + 256);               // 256 B
  int* offsets = (int*)(ws + 512);              // 260 B
  int* sel_e = (int*)(ws + 1024);               // 64 KB
  float* sel_w = (float*)(ws + 1024 + 65536);   // 64 KB
  int* token_of = (int*)(ws + 1024 + 2 * 65536);
  float* weight_of = (float*)(ws + 1024 + 3 * 65536);
  ushort_t* act = (ushort_t*)(ws + 524288);     // 16384*1024*2 = 32 MB

  hipMemsetAsync(out, 0, (size_t)T_TOK * H_DIM * sizeof(float), stream);
  hipMemsetAsync(ws, 0, 1024, stream);

  router_kernel<<<T_TOK / 4, 256, 0, stream>>>(X, GW, logits);
  topk_kernel<<<T_TOK / 4, 256, 0, stream>>>(logits, counts, sel_e, sel_w);
  scan_kernel<<<1, 64, 0, stream>>>(counts, offsets, cursor);
  assign_kernel<<<(T_TOK * TOPK) / 256, 256, 0, stream>>>(sel_e, sel_w, offsets, cursor,
                                                          token_of, weight_of);
  gateup_kernel<<<N_EXP * MT * 8, 512, 0, stream>>>(X, Wg, Wu, offsets, token_of, act);
  down_kernel<<<N_EXP * MTG * 16, 512, 0, stream>>>(act, Wd, offsets, token_of,
                                                    weight_of, out);
}

// Round 22
// 814.259 us; speedup vs baseline: 1.2999x; 1.0063x over previous
//
#include <hip/hip_runtime.h>

typedef unsigned short ushort_t;
typedef unsigned int uint_t;

typedef __attribute__((ext_vector_type(8))) __bf16 bf16x8_t;
typedef __attribute__((ext_vector_type(8))) short s16x8;
typedef __attribute__((ext_vector_type(4))) float f32x4;

#define T_TOK 2048
#define H_DIM 2048
#define I_DIM 1024
#define N_EXP 64
#define TOPK 8
#define MT 6         // gateup: 128-row m-tiles (covers 768 tokens/expert)
#define MTG 3        // down: 256-row m-tiles
#define LSTR 40      // LDS row stride in bf16 elems (BK=32 + 8 pad)

// Raw barrier: does NOT drain vmcnt -> in-flight global loads stay outstanding.
#define BAR_RAW()  asm volatile("s_barrier" ::: "memory")
// LDS-visibility barrier: drain ds ops (lgkm) then barrier; vmcnt untouched.
#define BAR_LGKM() asm volatile("s_waitcnt lgkmcnt(0)\n\ts_barrier" ::: "memory")

__device__ inline f32x4 mfma_bf16(s16x8 a, s16x8 b, f32x4 c) {
  return __builtin_amdgcn_mfma_f32_16x16x32_bf16(
      __builtin_bit_cast(bf16x8_t, a), __builtin_bit_cast(bf16x8_t, b), c, 0, 0, 0);
}

__device__ inline ushort_t f2bf(float f) {
  uint_t u = __float_as_uint(f);
  u += 0x7FFFu + ((u >> 16) & 1u);   // round-to-nearest-even
  return (ushort_t)(u >> 16);
}

// packed f32x2 -> bf16x2 (RNE), 1 instruction
__device__ inline uint_t pkbf(float a, float b) {
  uint_t r;
  asm("v_cvt_pk_bf16_f32 %0, %1, %2" : "=v"(r) : "v"(a), "v"(b));
  return r;
}
// float4 -> 4 bf16 (8 B)
__device__ inline uint2 pk4(float4 v) {
  uint2 w;
  w.x = pkbf(v.x, v.y);
  w.y = pkbf(v.z, v.w);
  return w;
}

// XCD-chunk swizzle (bijective when nwg % 8 == 0)
__device__ __forceinline__ int xcd_swizzle(int bid, int nwg) {
  int q = nwg >> 3;
  return (bid & 7) * q + (bid >> 3);
}

// ---------------- Router: logits[t][e] = sum_h x[t][h] * gw[e][h] (fp32 exact) ----------
__global__ __launch_bounds__(256) void router_kernel(const float* __restrict__ X,
                                                     const float* __restrict__ GW,
                                                     float* __restrict__ logits) {
  __shared__ float xs[4][H_DIM];
  int tid = threadIdx.x;
  int t0 = blockIdx.x * 4;
  const float4* src = (const float4*)(X + (size_t)t0 * H_DIM);
  float4* dst = (float4*)(&xs[0][0]);
#pragma unroll
  for (int j = 0; j < 8; ++j) dst[tid + 256 * j] = src[tid + 256 * j];
  __syncthreads();
  int wave = tid >> 6, lane = tid & 63;
  int t = t0 + wave;
  const float4* w = (const float4*)(GW + (size_t)lane * H_DIM);
  const float4* xr = (const float4*)(&xs[wave][0]);
  float acc = 0.f;
  for (int i = 0; i < H_DIM / 4; ++i) {
    float4 a = xr[i];
    float4 b = w[i];
    acc = fmaf(a.x, b.x, acc);
    acc = fmaf(a.y, b.y, acc);
    acc = fmaf(a.z, b.z, acc);
    acc = fmaf(a.w, b.w, acc);
  }
  logits[(size_t)t * N_EXP + lane] = acc;
}

// ---------------- Softmax + top-8 per token (one wave per token) -----------------------
__global__ __launch_bounds__(256) void topk_kernel(const float* __restrict__ logits,
                                                   int* __restrict__ counts,
                                                   int* __restrict__ sel_e,
                                                   float* __restrict__ sel_w) {
  int tid = threadIdx.x;
  int wave = tid >> 6, lane = tid & 63;
  int t = blockIdx.x * 4 + wave;
  float l = logits[(size_t)t * N_EXP + lane];
  float m = l;
#pragma unroll
  for (int s = 32; s; s >>= 1) m = fmaxf(m, __shfl_xor(m, s, 64));
  float p = __expf(l - m);
  float sum = p;
#pragma unroll
  for (int s = 32; s; s >>= 1) sum += __shfl_xor(sum, s, 64);
  float prob = p / sum;

  float val = l;
#pragma unroll
  for (int k = 0; k < TOPK; ++k) {
    float bv = val;
    int bi = lane;
#pragma unroll
    for (int s = 32; s; s >>= 1) {
      float ov = __shfl_xor(bv, s, 64);
      int oi = __shfl_xor(bi, s, 64);
      if (ov > bv || (ov == bv && oi < bi)) { bv = ov; bi = oi; }
    }
    float bw = __shfl(prob, bi, 64);
    if (lane == 0) {
      sel_e[t * TOPK + k] = bi;
      sel_w[t * TOPK + k] = bw;
      atomicAdd(&counts[bi], 1);
    }
    if (lane == bi) val = -INFINITY;
  }
}

// ---------------- Prefix sum over 64 expert counts -------------------------------------
__global__ void scan_kernel(const int* __restrict__ counts, int* __restrict__ offsets,
                            int* __restrict__ cursor) {
  if (threadIdx.x == 0) {
    int acc = 0;
    for (int e = 0; e < N_EXP; ++e) { offsets[e] = acc; acc += counts[e]; }
    offsets[N_EXP] = acc;
  }
  if (threadIdx.x < N_EXP) cursor[threadIdx.x] = 0;
}

// ---------------- Assign packed rows ---------------------------------------------------
__global__ __launch_bounds__(256) void assign_kernel(const int* __restrict__ sel_e,
                                                     const float* __restrict__ sel_w,
                                                     const int* __restrict__ offsets,
                                                     int* __restrict__ cursor,
                                                     int* __restrict__ token_of,
                                                     float* __restrict__ weight_of) {
  int idx = blockIdx.x * 256 + threadIdx.x;  // 0..16383
  int t = idx >> 3;
  int e = sel_e[idx];
  float w = sel_w[idx];
  int r = offsets[e] + atomicAdd(&cursor[e], 1);
  token_of[r] = t;
  weight_of[r] = w;
}

// ---------------- Fused gate+up GEMM + SiLU -> act (bf16) — best measured (R16/R18) ----
// 512 thr, tile 128(M)x128(N) x2 proj, BK=32, 8 waves (2M x 4N), wave 64x32/proj
// (acc = 16 f32x4), 2-deep register prefetch, (512,3), nt-fastest + XCD swizzle.
__global__ __launch_bounds__(512, 3) void gateup_kernel(const float* __restrict__ X,
                                                        const float* __restrict__ Wg,
                                                        const float* __restrict__ Wu,
                                                        const int* __restrict__ offsets,
                                                        const int* __restrict__ token_of,
                                                        ushort_t* __restrict__ act) {
  int bid = xcd_swizzle(blockIdx.x, N_EXP * MT * 8);
  int e = bid / (MT * 8);
  int mt = (bid % (MT * 8)) / 8;   // nt fastest
  int nt = bid % 8;
  int base = offsets[e];
  int Me = offsets[e + 1] - base;
  if (mt * 128 >= Me) return;

  __shared__ ushort_t As[128 * LSTR];   // 10 KB
  __shared__ ushort_t Bgs[128 * LSTR];  // 10 KB
  __shared__ ushort_t Bus[128 * LSTR];  // 10 KB
  __shared__ int stok[128];

  int tid = threadIdx.x;
  if (tid < 128) {
    int gm = mt * 128 + tid;
    int cm = gm < Me ? gm : (Me - 1);
    stok[tid] = token_of[base + cm];
  }
  __syncthreads();

  int wave = tid >> 6, lane = tid & 63;
  int wm = wave >> 2, wn = wave & 3;

  int sr = tid >> 2, sc = (tid & 3) * 8;
  const float* pA = X + (size_t)stok[sr] * H_DIM + sc;
  const float* pG = Wg + ((size_t)e * I_DIM + nt * 128 + sr) * H_DIM + sc;
  const float* pU = Wu + ((size_t)e * I_DIM + nt * 128 + sr) * H_DIM + sc;

  f32x4 accg[4][2], accu[4][2];
#pragma unroll
  for (int i = 0; i < 4; ++i)
#pragma unroll
    for (int j = 0; j < 2; ++j) { accg[i][j] = (f32x4)0.f; accu[i][j] = (f32x4)0.f; }

  // 2-deep prefetch: set0 = even tiles, set1 = odd tiles
  float4 a0[2], g0[2], u0[2], a1[2], g1[2], u1[2];
#pragma unroll
  for (int j = 0; j < 2; ++j) {
    a0[j] = *(const float4*)(pA + 4 * j);
    g0[j] = *(const float4*)(pG + 4 * j);
    u0[j] = *(const float4*)(pU + 4 * j);
    a1[j] = *(const float4*)(pA + 32 + 4 * j);
    g1[j] = *(const float4*)(pG + 32 + 4 * j);
    u1[j] = *(const float4*)(pU + 32 + 4 * j);
  }

  int fr = lane & 15, q2 = lane >> 4;
  const int NK = H_DIM / 32;  // 64 (even)

#define GU_COMPUTE()                                                                \
  {                                                                                 \
    s16x8 af[4], bg[2], bu[2];                                                      \
    _Pragma("unroll")                                                               \
    for (int mf = 0; mf < 4; ++mf)                                                  \
      af[mf] = *(const s16x8*)&As[(wm * 64 + mf * 16 + fr) * LSTR + q2 * 8];        \
    _Pragma("unroll")                                                               \
    for (int nf = 0; nf < 2; ++nf) {                                                \
      bg[nf] = *(const s16x8*)&Bgs[(wn * 32 + nf * 16 + fr) * LSTR + q2 * 8];       \
      bu[nf] = *(const s16x8*)&Bus[(wn * 32 + nf * 16 + fr) * LSTR + q2 * 8];       \
    }                                                                               \
    __builtin_amdgcn_s_setprio(1);                                                  \
    _Pragma("unroll")                                                               \
    for (int mf = 0; mf < 4; ++mf)                                                  \
      _Pragma("unroll")                                                             \
      for (int nf = 0; nf < 2; ++nf) {                                              \
        accg[mf][nf] = mfma_bf16(af[mf], bg[nf], accg[mf][nf]);                     \
        accu[mf][nf] = mfma_bf16(af[mf], bu[nf], accu[mf][nf]);                     \
      }                                                                             \
    __builtin_amdgcn_s_setprio(0);                                                  \
  }

  for (int k = 0; k < NK; k += 2) {
    // even tile k (set0): ds_write's vmcnt wait targets loads issued at k-2
    BAR_RAW();
    *(uint2*)&As[sr * LSTR + sc] = pk4(a0[0]);
    *(uint2*)&As[sr * LSTR + sc + 4] = pk4(a0[1]);
    *(uint2*)&Bgs[sr * LSTR + sc] = pk4(g0[0]);
    *(uint2*)&Bgs[sr * LSTR + sc + 4] = pk4(g0[1]);
    *(uint2*)&Bus[sr * LSTR + sc] = pk4(u0[0]);
    *(uint2*)&Bus[sr * LSTR + sc + 4] = pk4(u0[1]);
    if (k + 2 < NK) {
      int kn = (k + 2) * 32;
#pragma unroll
      for (int j = 0; j < 2; ++j) {
        a0[j] = *(const float4*)(pA + kn + 4 * j);
        g0[j] = *(const float4*)(pG + kn + 4 * j);
        u0[j] = *(const float4*)(pU + kn + 4 * j);
      }
    }
    BAR_LGKM();
    GU_COMPUTE();

    // odd tile k+1 (set1)
    BAR_RAW();
    *(uint2*)&As[sr * LSTR + sc] = pk4(a1[0]);
    *(uint2*)&As[sr * LSTR + sc + 4] = pk4(a1[1]);
    *(uint2*)&Bgs[sr * LSTR + sc] = pk4(g1[0]);
    *(uint2*)&Bgs[sr * LSTR + sc + 4] = pk4(g1[1]);
    *(uint2*)&Bus[sr * LSTR + sc] = pk4(u1[0]);
    *(uint2*)&Bus[sr * LSTR + sc + 4] = pk4(u1[1]);
    if (k + 3 < NK) {
      int kn = (k + 3) * 32;
#pragma unroll
      for (int j = 0; j < 2; ++j) {
        a1[j] = *(const float4*)(pA + kn + 4 * j);
        g1[j] = *(const float4*)(pG + kn + 4 * j);
        u1[j] = *(const float4*)(pU + kn + 4 * j);
      }
    }
    BAR_LGKM();
    GU_COMPUTE();
  }

  // epilogue: act = silu(g)*u -> bf16
#pragma unroll
  for (int mf = 0; mf < 4; ++mf)
#pragma unroll
    for (int nf = 0; nf < 2; ++nf) {
      f32x4 g = accg[mf][nf], u = accu[mf][nf];
#pragma unroll
      for (int r = 0; r < 4; ++r) {
        int mloc = wm * 64 + mf * 16 + q2 * 4 + r;
        int gm = mt * 128 + mloc;
        if (gm < Me) {
          float gv = g[r], uv = u[r];
          float s = gv / (1.f + __expf(-gv));
          int col = nt * 128 + wn * 32 + nf * 16 + fr;
          act[(size_t)(base + gm) * I_DIM + col] = f2bf(s * uv);
        }
      }
    }
#undef GU_COMPUTE
}

// ---------------- Down GEMM + weighted scatter — best measured (R17/R18) ---------------
// tile 256(M)x128(N), BK=32, 512 thr, 8 waves (2M x 4N), per-wave 128x32 ->
// acc = 16 f32x4 (64 AGPR). (512,3), 1-deep prefetch.
__global__ __launch_bounds__(512, 3) void down_kernel(const ushort_t* __restrict__ act,
                                                      const float* __restrict__ Wd,
                                                      const int* __restrict__ offsets,
                                                      const int* __restrict__ token_of,
                                                      const float* __restrict__ weight_of,
                                                      float* __restrict__ out) {
  int bid = xcd_swizzle(blockIdx.x, N_EXP * MTG * 16);
  int e = bid / (MTG * 16);
  int mt = (bid % (MTG * 16)) / 16;  // nt fastest
  int nt = bid % 16;
  int base = offsets[e];
  int Me = offsets[e + 1] - base;
  if (mt * 256 >= Me) return;

  __shared__ ushort_t As[256 * LSTR];   // 20 KB
  __shared__ ushort_t Bs[128 * LSTR];   // 10 KB
  __shared__ int stok[256];
  __shared__ float sw[256];

  int tid = threadIdx.x;
  if (tid < 256) {
    int gm = mt * 256 + tid;
    int ok = gm < Me;
    int cm = ok ? gm : (Me - 1);
    stok[tid] = token_of[base + cm];
    sw[tid] = ok ? weight_of[base + gm] : 0.f;
  }
  __syncthreads();

  int wave = tid >> 6, lane = tid & 63;
  int wm = wave >> 2, wn = wave & 3;

  // A (act, bf16): 2 thr/row x 256 rows; 16 bf16 (32 B = 2 s16x8) at (tid&1)*16.
  int sa = tid >> 1;
  int ca = (tid & 1) * 16;
  int r0 = mt * 256 + sa;
  if (r0 >= Me) r0 = Me - 1;
  const ushort_t* pA = act + (size_t)(base + r0) * I_DIM + ca;
  // B (Wd, fp32): 4 thr/row x 128 rows; 8 floats at (tid&3)*8.
  int sb = tid >> 2, cb = (tid & 3) * 8;
  const float* pB = Wd + ((size_t)e * H_DIM + nt * 128 + sb) * I_DIM + cb;

  f32x4 acc[8][2];
#pragma unroll
  for (int i = 0; i < 8; ++i)
#pragma unroll
    for (int j = 0; j < 2; ++j) acc[i][j] = (f32x4)0.f;

  s16x8 rA[2];
  float4 rB[2];
  rA[0] = *(const s16x8*)pA;
  rA[1] = *(const s16x8*)(pA + 8);
#pragma unroll
  for (int j = 0; j < 2; ++j) rB[j] = *(const float4*)(pB + 4 * j);

  int fr = lane & 15, q2 = lane >> 4;

  for (int k0 = 0; k0 < I_DIM; k0 += 32) {
    BAR_RAW();
    *(s16x8*)&As[sa * LSTR + ca] = rA[0];
    *(s16x8*)&As[sa * LSTR + ca + 8] = rA[1];
    *(uint2*)&Bs[sb * LSTR + cb] = pk4(rB[0]);
    *(uint2*)&Bs[sb * LSTR + cb + 4] = pk4(rB[1]);
    if (k0 + 32 < I_DIM) {
      int kn = k0 + 32;
      rA[0] = *(const s16x8*)(pA + kn);
      rA[1] = *(const s16x8*)(pA + kn + 8);
#pragma unroll
      for (int j = 0; j < 2; ++j) rB[j] = *(const float4*)(pB + kn + 4 * j);
    }
    BAR_LGKM();

    s16x8 bf[2];
#pragma unroll
    for (int nf = 0; nf < 2; ++nf)
      bf[nf] = *(const s16x8*)&Bs[(wn * 32 + nf * 16 + fr) * LSTR + q2 * 8];
    __builtin_amdgcn_s_setprio(1);
#pragma unroll
    for (int mf = 0; mf < 8; ++mf) {
      s16x8 af = *(const s16x8*)&As[(wm * 128 + mf * 16 + fr) * LSTR + q2 * 8];
#pragma unroll
      for (int nf = 0; nf < 2; ++nf)
        acc[mf][nf] = mfma_bf16(af, bf[nf], acc[mf][nf]);
    }
    __builtin_amdgcn_s_setprio(0);
  }

#pragma unroll
  for (int mf = 0; mf < 8; ++mf)
#pragma unroll
    for (int nf = 0; nf < 2; ++nf) {
      f32x4 v = acc[mf][nf];
#pragma unroll
      for (int r = 0; r < 4; ++r) {
        int mloc = wm * 128 + mf * 16 + q2 * 4 + r;
        int gm = mt * 256 + mloc;
        if (gm < Me) {
          int t = stok[mloc];
          float w = sw[mloc];
          int h = nt * 128 + wn * 32 + nf * 16 + fr;
          unsafeAtomicAdd(&out[(size_t)t * H_DIM + h], w * v[r]);
        }
      }
    }
}

// ---------------------------------------------------------------------------------------
extern "C" void kernel_launch(void* const* d_in, const int* in_sizes, int n_in,
                              void* d_out, int out_size, void* d_ws, size_t ws_size,
                              hipStream_t stream) {
  const float* X = (const float*)d_in[0];
  const float* GW = (const float*)d_in[1];
  const float* Wg = (const float*)d_in[2];
  const float* Wu = (const float*)d_in[3];
  const float* Wd = (const float*)d_in[4];
  float* out = (float*)d_out;
  float* logits = out + (size_t)T_TOK * H_DIM;

  char* ws = (char*)d_ws;
  int* counts = (int*)ws;                       // 256 B
  int* cursor = (int*)(ws + 256);               // 256 B
  int* offsets = (int*)(ws + 512);              // 260 B
  int* sel_e = (int*)(ws + 1024);               // 64 KB
  float* sel_w = (float*)(ws + 1024 + 65536);   // 64 KB
  int* token_of = (int*)(ws + 1024 + 2 * 65536);
  float* weight_of = (float*)(ws + 1024 + 3 * 65536);
  ushort_t* act = (ushort_t*)(ws + 524288);     // 16384*1024*2 = 32 MB

  hipMemsetAsync(out, 0, (size_t)T_TOK * H_DIM * sizeof(float), stream);
  hipMemsetAsync(ws, 0, 1024, stream);

  router_kernel<<<T_TOK / 4, 256, 0, stream>>>(X, GW, logits);
  topk_kernel<<<T_TOK / 4, 256, 0, stream>>>(logits, counts, sel_e, sel_w);
  scan_kernel<<<1, 64, 0, stream>>>(counts, offsets, cursor);
  assign_kernel<<<(T_TOK * TOPK) / 256, 256, 0, stream>>>(sel_e, sel_w, offsets, cursor,
                                                          token_of, weight_of);
  gateup_kernel<<<N_EXP * MT * 8, 512, 0, stream>>>(X, Wg, Wu, offsets, token_of, act);
  down_kernel<<<N_EXP * MTG * 16, 512, 0, stream>>>(act, Wd, offsets, token_of,
                                                    weight_of, out);
}